// Round 1
// baseline (846.169 us; speedup 1.0000x reference)
//
#include <hip/hip_runtime.h>
#include <hip/hip_bf16.h>
#include <cstdint>
#include <cstddef>

#define E_ 8
#define M_ 1024
#define H_ 2048
#define I2_ 4096
#define INTER_ 2048

typedef __attribute__((ext_vector_type(8))) __bf16 bf16x8;
typedef __attribute__((ext_vector_type(4))) float f32x4;

__device__ __forceinline__ unsigned short f2bf(float x) {
  union { float f; unsigned u; } v; v.f = x;
  unsigned r = v.u + 0x7fffu + ((v.u >> 16) & 1u);   // RNE
  return (unsigned short)(r >> 16);
}

// ---------------- f32 -> bf16 elementwise (dispatched) ----------------
__global__ void k_cvt(const float* __restrict__ src, unsigned short* __restrict__ dst, int n4) {
  int i = blockIdx.x * blockDim.x + threadIdx.x;
  int stride = gridDim.x * blockDim.x;
  const float4* s4 = (const float4*)src;
  ushort4* d4 = (ushort4*)dst;
  for (; i < n4; i += stride) {
    float4 v = s4[i];
    ushort4 o;
    o.x = f2bf(v.x); o.y = f2bf(v.y); o.z = f2bf(v.z); o.w = f2bf(v.w);
    d4[i] = o;
  }
}

// ------------- transpose+convert: per expert (Ks x Ns) f32 -> (Ns x Ks) bf16 -------------
// REMAP=1 folds the gate/up de-interleave: output row r takes source column
// (r & ~31) | ((r&15)<<1) | ((r>>4)&1)   (local within aligned 32-blocks).
template<int REMAP>
__global__ __launch_bounds__(1024) void k_transpose(const float* __restrict__ src,
                                                    unsigned short* __restrict__ dst,
                                                    int Ks, int Ns) {
  __shared__ float t[32][65];
  int e = blockIdx.z;
  const float* s = src + (size_t)e * Ks * Ns;
  unsigned short* d = dst + (size_t)e * Ks * Ns;
  int k0 = blockIdx.x * 64;
  int n0 = blockIdx.y * 32;
  int tx = threadIdx.x, ty = threadIdx.y;
  t[tx][ty]      = s[(size_t)(k0 + ty) * Ns + n0 + tx];
  t[tx][ty + 32] = s[(size_t)(k0 + ty + 32) * Ns + n0 + tx];
  __syncthreads();
  int sl = REMAP ? (((ty & 15) << 1) | (ty >> 4)) : ty;
  unsigned short lo = f2bf(t[sl][2 * tx]);
  unsigned short hi = f2bf(t[sl][2 * tx + 1]);
  unsigned v = (unsigned)lo | ((unsigned)hi << 16);
  *(unsigned*)(d + (size_t)(n0 + ty) * Ks + k0 + 2 * tx) = v;
}

// ---------------- MFMA GEMM: C = A(bf16, MxK) * Bt(bf16, NxK)^T ----------------
// BM=BN=128, BK=64, 256 threads, 2x2 waves x 4x4 MFMA 16x16x32.
// ACT=1: fused bias + clamp + gated-SiLU epilogue -> bf16 act (N/2 cols).
// ACT=0: bias epilogue -> f32 out.
template<int ACT, int N, int K>
__global__ __launch_bounds__(256) void k_gemm(
    const unsigned short* __restrict__ A,   // E x M x K
    const unsigned short* __restrict__ Bt,  // E x N x K
    const float* __restrict__ bias,         // E x N
    unsigned short* __restrict__ ActOut,    // E x M x N/2 (ACT)
    float* __restrict__ Out)                // E x M x N  (!ACT)
{
  __shared__ unsigned short la[128 * 64];
  __shared__ unsigned short lb[128 * 64];
  const int tid = threadIdx.x;
  const int lane = tid & 63;
  const int wv = tid >> 6;
  const int wm = wv & 1, wn = wv >> 1;
  const int e = blockIdx.z;
  const int n0 = blockIdx.x * 128;
  const int m0 = blockIdx.y * 128;
  const unsigned short* Ae = A + (size_t)e * M_ * K + (size_t)m0 * K;
  const unsigned short* Be = Bt + (size_t)e * N * K + (size_t)n0 * K;

  // Staging: 1024 16B-slots per operand; slot s holds row m=s>>3, chunk j=(s&7)^(m&7)
  const unsigned short* ga[4];
  const unsigned short* gb[4];
  int segb[4];
  #pragma unroll
  for (int t = 0; t < 4; ++t) {
    int s = (wv * 4 + t) * 64 + lane;
    int m = s >> 3;
    int j = (s & 7) ^ (m & 7);
    ga[t] = Ae + (size_t)m * K + j * 8;
    gb[t] = Be + (size_t)m * K + j * 8;
    segb[t] = (wv * 4 + t) * 1024;  // LDS byte offset of this wave-instruction's segment
  }

  const int c = lane & 15;
  const int q = lane >> 4;

  f32x4 acc[4][4];
  const f32x4 zero = {0.f, 0.f, 0.f, 0.f};
  #pragma unroll
  for (int i = 0; i < 4; ++i)
    #pragma unroll
    for (int j = 0; j < 4; ++j) acc[i][j] = zero;

  const int KT = K / 64;
  for (int kt = 0; kt < KT; ++kt) {
    #pragma unroll
    for (int t = 0; t < 4; ++t) {
      __builtin_amdgcn_global_load_lds(
          (const __attribute__((address_space(1))) void*)(const void*)(ga[t] + kt * 64),
          (__attribute__((address_space(3))) void*)(void*)((char*)la + segb[t]), 16, 0, 0);
      __builtin_amdgcn_global_load_lds(
          (const __attribute__((address_space(1))) void*)(const void*)(gb[t] + kt * 64),
          (__attribute__((address_space(3))) void*)(void*)((char*)lb + segb[t]), 16, 0, 0);
    }
    __syncthreads();
    #pragma unroll
    for (int ks = 0; ks < 2; ++ks) {
      bf16x8 av[4], bv[4];
      #pragma unroll
      for (int mi = 0; mi < 4; ++mi) {
        int row = wm * 64 + mi * 16 + c;
        int slot = row * 8 + ((ks * 4 + q) ^ (c & 7));
        av[mi] = *(const bf16x8*)(la + slot * 8);
      }
      #pragma unroll
      for (int ni = 0; ni < 4; ++ni) {
        int row = wn * 64 + ni * 16 + c;
        int slot = row * 8 + ((ks * 4 + q) ^ (c & 7));
        bv[ni] = *(const bf16x8*)(lb + slot * 8);
      }
      #pragma unroll
      for (int mi = 0; mi < 4; ++mi)
        #pragma unroll
        for (int ni = 0; ni < 4; ++ni)
          acc[mi][ni] = __builtin_amdgcn_mfma_f32_16x16x32_bf16(av[mi], bv[ni], acc[mi][ni], 0, 0, 0);
    }
    __syncthreads();
  }

  if (ACT) {
    unsigned short* ActE = ActOut + (size_t)e * M_ * (N / 2);
    const float* be = bias + (size_t)e * N;
    int colbase = n0 + wn * 64;
    #pragma unroll
    for (int p = 0; p < 2; ++p) {
      int rg = colbase + 32 * p + c;               // gate column in rearranged gu
      int norig = (rg & ~31) | (c << 1);           // original interleaved column
      float bg = be[norig];
      float bu = be[norig + 1];
      int acol = ((rg >> 5) << 4) + c;             // activated column
      #pragma unroll
      for (int mi = 0; mi < 4; ++mi) {
        int rowb = m0 + wm * 64 + mi * 16 + q * 4;
        #pragma unroll
        for (int r = 0; r < 4; ++r) {
          float g = acc[mi][2 * p][r] + bg;
          float u = acc[mi][2 * p + 1][r] + bu;
          g = fminf(g, 7.0f);
          u = fminf(fmaxf(u, -7.0f), 7.0f);
          float glu = g / (1.0f + __expf(-1.702f * g));
          float a = (u + 1.0f) * glu;
          ActE[(size_t)(rowb + r) * (N / 2) + acol] = f2bf(a);
        }
      }
    }
  } else {
    float* OutE = Out + (size_t)e * M_ * N;
    const float* be = bias + (size_t)e * N;
    #pragma unroll
    for (int ni = 0; ni < 4; ++ni) {
      int col = n0 + wn * 64 + ni * 16 + c;
      float bb = be[col];
      #pragma unroll
      for (int mi = 0; mi < 4; ++mi) {
        int rowb = m0 + wm * 64 + mi * 16 + q * 4;
        #pragma unroll
        for (int r = 0; r < 4; ++r)
          OutE[(size_t)(rowb + r) * N + col] = acc[mi][ni][r] + bb;
      }
    }
  }
}

// ---------------- scratch-free fallback (correct but slow) ----------------
__global__ __launch_bounds__(256) void k_naive(const float* __restrict__ disp,
    const float* __restrict__ w1, const float* __restrict__ w1b,
    const float* __restrict__ w2, const float* __restrict__ w2b,
    float* __restrict__ out) {
  __shared__ float xrow[H_];
  __shared__ float act[INTER_];
  int b = blockIdx.x;
  int e = b / M_;
  int m = b % M_;
  const float* x = disp + (size_t)(e * M_ + m) * H_;
  int tid = threadIdx.x;
  for (int k = tid; k < H_; k += 256) xrow[k] = x[k];
  __syncthreads();
  const float* w1e = w1 + (size_t)e * H_ * I2_;
  const float* b1e = w1b + (size_t)e * I2_;
  for (int jj = 0; jj < INTER_ / 256; ++jj) {
    int i = tid + jj * 256;
    float g = b1e[2 * i], u = b1e[2 * i + 1];
    for (int k = 0; k < H_; ++k) {
      float xv = xrow[k];
      g += xv * w1e[(size_t)k * I2_ + 2 * i];
      u += xv * w1e[(size_t)k * I2_ + 2 * i + 1];
    }
    g = fminf(g, 7.0f);
    u = fminf(fmaxf(u, -7.0f), 7.0f);
    float glu = g / (1.0f + __expf(-1.702f * g));
    act[i] = (u + 1.0f) * glu;
  }
  __syncthreads();
  const float* w2e = w2 + (size_t)e * INTER_ * H_;
  const float* b2e = w2b + (size_t)e * H_;
  float* oute = out + (size_t)(e * M_ + m) * H_;
  for (int jj = 0; jj < H_ / 256; ++jj) {
    int h = tid + jj * 256;
    float o = b2e[h];
    for (int i = 0; i < INTER_; ++i) o += act[i] * w2e[(size_t)i * H_ + h];
    oute[h] = o;
  }
}

extern "C" void kernel_launch(void* const* d_in, const int* in_sizes, int n_in,
                              void* d_out, int out_size, void* d_ws, size_t ws_size,
                              hipStream_t stream) {
  const float* disp = (const float*)d_in[0];
  const float* w1   = (const float*)d_in[1];
  const float* w1b  = (const float*)d_in[2];
  const float* w2   = (const float*)d_in[3];
  const float* w2b  = (const float*)d_in[4];
  float* out = (float*)d_out;

  const size_t nA   = (size_t)E_ * M_ * H_;       // 16.7M
  const size_t nW1  = (size_t)E_ * H_ * I2_;      // 67.1M
  const size_t nW2  = (size_t)E_ * INTER_ * H_;   // 33.5M
  const size_t nAct = (size_t)E_ * M_ * INTER_;   // 16.7M
  const size_t need = (nA + nW1 + nW2 + nAct) * 2; // 256 MB

  if (ws_size >= need) {
    unsigned short* actb = (unsigned short*)d_ws;
    unsigned short* w1t  = actb + nAct;
    unsigned short* w2t  = w1t + nW1;
    unsigned short* ab   = w2t + nW2;

    k_cvt<<<4096, 256, 0, stream>>>(disp, ab, (int)(nA / 4));
    k_transpose<1><<<dim3(H_ / 64, I2_ / 32, E_), dim3(32, 32), 0, stream>>>(w1, w1t, H_, I2_);
    k_transpose<0><<<dim3(INTER_ / 64, H_ / 32, E_), dim3(32, 32), 0, stream>>>(w2, w2t, INTER_, H_);
    k_gemm<1, I2_, H_><<<dim3(I2_ / 128, M_ / 128, E_), 256, 0, stream>>>(ab, w1t, w1b, actb, nullptr);
    k_gemm<0, H_, INTER_><<<dim3(H_ / 128, M_ / 128, E_), 256, 0, stream>>>(actb, w2t, w2b, nullptr, out);
  } else {
    k_naive<<<E_ * M_, 256, 0, stream>>>(disp, w1, w1b, w2, w2b, out);
  }
}

// Round 2
// 814.325 us; speedup vs baseline: 1.0391x; 1.0391x over previous
//
#include <hip/hip_runtime.h>
#include <hip/hip_bf16.h>
#include <cstdint>
#include <cstddef>

#define E_ 8
#define M_ 1024
#define H_ 2048
#define I2_ 4096
#define INTER_ 2048

typedef __attribute__((ext_vector_type(8))) __bf16 bf16x8;
typedef __attribute__((ext_vector_type(4))) float f32x4;

__device__ __forceinline__ unsigned short f2bf(float x) {
  union { float f; unsigned u; } v; v.f = x;
  unsigned r = v.u + 0x7fffu + ((v.u >> 16) & 1u);   // RNE
  return (unsigned short)(r >> 16);
}

// pack two f32 -> (lo,hi) bf16 pair; maps to v_cvt_pk_bf16_f32 on gfx950
__device__ __forceinline__ unsigned pk2(float lo, float hi) {
  __hip_bfloat162 h = __float22bfloat162_rn(make_float2(lo, hi));
  union { __hip_bfloat162 h2; unsigned u; } c; c.h2 = h; return c.u;
}

// LDS B tile: dword (= bf16 k-pair) at [kp][r], kp in [0,32), r in [0,128).
// XOR swizzle: reads (fixed q=kp>>2 group) 2-way only; writes spread all 8 bank-quads.
__device__ __forceinline__ int bofs(int kp, int r) {
  int f = (20 * ((kp >> 2) & 3)) ^ ((kp & 1) << 4);
  return kp * 128 + (r ^ f);
}

// ---------------- f32 -> bf16 elementwise (dispatched) ----------------
__global__ void k_cvt(const float* __restrict__ src, unsigned short* __restrict__ dst, int n4) {
  int i = blockIdx.x * blockDim.x + threadIdx.x;
  int stride = gridDim.x * blockDim.x;
  const float4* s4 = (const float4*)src;
  ushort4* d4 = (ushort4*)dst;
  for (; i < n4; i += stride) {
    float4 v = s4[i];
    ushort4 o;
    o.x = f2bf(v.x); o.y = f2bf(v.y); o.z = f2bf(v.z); o.w = f2bf(v.w);
    d4[i] = o;
  }
}

// ---------------- MFMA GEMM: C = A(bf16, MxK) * B(f32, KxN) ----------------
// B is consumed directly in K-major f32 layout: per K-tile, threads load
// coalesced float4 pairs (rows k,k+1), cvt+pack to bf16 k-pairs, ds_write_b128
// into the swizzled k-pair LDS layout. ACT=1 folds the gate/up de-interleave
// into the read pattern (even cols -> rows r, odd -> r+16 within 32-blocks).
template<int ACT, int N, int K>
__global__ __launch_bounds__(256) void k_gemm(
    const unsigned short* __restrict__ A,   // E x M x K  (bf16)
    const float* __restrict__ Bf,           // E x K x N  (f32)
    const float* __restrict__ bias,         // E x N
    unsigned short* __restrict__ ActOut,    // E x M x N/2 (ACT)
    float* __restrict__ Out)                // E x M x N  (!ACT)
{
  __shared__ unsigned short la[128 * 64];
  __shared__ unsigned lb32[32 * 128];
  const int tid = threadIdx.x;
  const int lane = tid & 63;
  const int wv = tid >> 6;
  const int wm = wv & 1, wn = wv >> 1;
  const int e = blockIdx.z;
  const int n0 = blockIdx.x * 128;
  const int m0 = blockIdx.y * 128;
  const unsigned short* Ae = A + (size_t)e * M_ * K + (size_t)m0 * K;
  const float* Be = Bf + (size_t)e * K * N + n0;

  // ---- A staging via global_load_lds (slot s holds row m=s>>3, chunk j=(s&7)^(m&7)) ----
  const unsigned short* ga[4];
  int segb[4];
  #pragma unroll
  for (int t = 0; t < 4; ++t) {
    int s = (wv * 4 + t) * 64 + lane;
    int m = s >> 3;
    int j = (s & 7) ^ (m & 7);
    ga[t] = Ae + (size_t)m * K + j * 8;
    segb[t] = (wv * 4 + t) * 1024;
  }

  // ---- B staging geometry ----
  int kpb, colb, rg;
  if (ACT) {        // 2 units/thread: kp = kpb + 16*uu; 8 interleaved cols -> gate+up quads
    kpb = tid >> 4;                 // 0..15
    int g = tid & 15;
    colb = 8 * g;
    rg = 32 * (g >> 2) + 4 * (g & 3);
  } else {          // 4 units/thread: kp = kpb + 8*uu; 4 cols
    kpb = tid >> 5;                 // 0..7
    colb = 4 * (tid & 31);
    rg = colb;
  }
  const float* bg = Be + (size_t)(2 * kpb) * N + colb;

  const int c = lane & 15;
  const int q = lane >> 4;

  f32x4 acc[4][4];
  const f32x4 zero = {0.f, 0.f, 0.f, 0.f};
  #pragma unroll
  for (int i = 0; i < 4; ++i)
    #pragma unroll
    for (int j = 0; j < 4; ++j) acc[i][j] = zero;

  #define LD4(p, off) (*(const float4*)((p) + (off)))

  float4 pb[8];
  // prologue: load B f32 for kt=0
  {
    const float* p = bg;
    if (ACT) {
      pb[0] = LD4(p, 0);                    pb[1] = LD4(p, 4);
      pb[2] = LD4(p, (size_t)N);            pb[3] = LD4(p, (size_t)N + 4);
      pb[4] = LD4(p, (size_t)32 * N);       pb[5] = LD4(p, (size_t)32 * N + 4);
      pb[6] = LD4(p, (size_t)33 * N);       pb[7] = LD4(p, (size_t)33 * N + 4);
    } else {
      #pragma unroll
      for (int uu = 0; uu < 4; ++uu) {
        pb[2 * uu]     = LD4(p, (size_t)(16 * uu) * N);
        pb[2 * uu + 1] = LD4(p, (size_t)(16 * uu + 1) * N);
      }
    }
  }

  const int KT = K / 64;
  for (int kt = 0; kt < KT; ++kt) {
    // stage A tile kt
    #pragma unroll
    for (int t = 0; t < 4; ++t) {
      __builtin_amdgcn_global_load_lds(
          (const __attribute__((address_space(1))) void*)(const void*)(ga[t] + kt * 64),
          (__attribute__((address_space(3))) void*)(void*)((char*)la + segb[t]), 16, 0, 0);
    }
    // stage B tile kt from prefetched registers
    if (ACT) {
      #pragma unroll
      for (int uu = 0; uu < 2; ++uu) {
        int kp = kpb + 16 * uu;
        float4 a0 = pb[4 * uu], a1 = pb[4 * uu + 1], b0 = pb[4 * uu + 2], b1 = pb[4 * uu + 3];
        uint4 gv, uv;
        gv.x = pk2(a0.x, b0.x); gv.y = pk2(a0.z, b0.z); gv.z = pk2(a1.x, b1.x); gv.w = pk2(a1.z, b1.z);
        uv.x = pk2(a0.y, b0.y); uv.y = pk2(a0.w, b0.w); uv.z = pk2(a1.y, b1.y); uv.w = pk2(a1.w, b1.w);
        *(uint4*)&lb32[bofs(kp, rg)] = gv;
        *(uint4*)&lb32[bofs(kp, rg + 16)] = uv;
      }
    } else {
      #pragma unroll
      for (int uu = 0; uu < 4; ++uu) {
        int kp = kpb + 8 * uu;
        float4 a = pb[2 * uu], b = pb[2 * uu + 1];
        uint4 v;
        v.x = pk2(a.x, b.x); v.y = pk2(a.y, b.y); v.z = pk2(a.z, b.z); v.w = pk2(a.w, b.w);
        *(uint4*)&lb32[bofs(kp, rg)] = v;
      }
    }
    __syncthreads();

    // prefetch B f32 for kt+1 (in flight across the MFMA section)
    if (kt + 1 < KT) {
      const float* p = bg + (size_t)(kt + 1) * 64 * N;
      if (ACT) {
        pb[0] = LD4(p, 0);                    pb[1] = LD4(p, 4);
        pb[2] = LD4(p, (size_t)N);            pb[3] = LD4(p, (size_t)N + 4);
        pb[4] = LD4(p, (size_t)32 * N);       pb[5] = LD4(p, (size_t)32 * N + 4);
        pb[6] = LD4(p, (size_t)33 * N);       pb[7] = LD4(p, (size_t)33 * N + 4);
      } else {
        #pragma unroll
        for (int uu = 0; uu < 4; ++uu) {
          pb[2 * uu]     = LD4(p, (size_t)(16 * uu) * N);
          pb[2 * uu + 1] = LD4(p, (size_t)(16 * uu + 1) * N);
        }
      }
    }

    // compute on tile kt
    #pragma unroll
    for (int ks = 0; ks < 2; ++ks) {
      bf16x8 av[4], bv[4];
      #pragma unroll
      for (int mi = 0; mi < 4; ++mi) {
        int row = wm * 64 + mi * 16 + c;
        int slot = row * 8 + ((ks * 4 + q) ^ (c & 7));
        av[mi] = *(const bf16x8*)(la + slot * 8);
      }
      #pragma unroll
      for (int ni = 0; ni < 4; ++ni) {
        int r = wn * 64 + ni * 16 + c;
        union { unsigned u[4]; bf16x8 v; } t;
        #pragma unroll
        for (int jp = 0; jp < 4; ++jp)
          t.u[jp] = lb32[bofs(ks * 16 + q * 4 + jp, r)];
        bv[ni] = t.v;
      }
      #pragma unroll
      for (int mi = 0; mi < 4; ++mi)
        #pragma unroll
        for (int ni = 0; ni < 4; ++ni)
          acc[mi][ni] = __builtin_amdgcn_mfma_f32_16x16x32_bf16(av[mi], bv[ni], acc[mi][ni], 0, 0, 0);
    }
    __syncthreads();
  }
  #undef LD4

  if (ACT) {
    unsigned short* ActE = ActOut + (size_t)e * M_ * (N / 2);
    const float* be = bias + (size_t)e * N;
    int colbase = n0 + wn * 64;
    #pragma unroll
    for (int p = 0; p < 2; ++p) {
      int rgc = colbase + 32 * p + c;              // gate column in rearranged gu
      int norig = (rgc & ~31) | (c << 1);          // original interleaved column
      float bg_ = be[norig];
      float bu_ = be[norig + 1];
      int acol = ((rgc >> 5) << 4) + c;            // activated column
      #pragma unroll
      for (int mi = 0; mi < 4; ++mi) {
        int rowb = m0 + wm * 64 + mi * 16 + q * 4;
        #pragma unroll
        for (int r = 0; r < 4; ++r) {
          float g = acc[mi][2 * p][r] + bg_;
          float u = acc[mi][2 * p + 1][r] + bu_;
          g = fminf(g, 7.0f);
          u = fminf(fmaxf(u, -7.0f), 7.0f);
          float glu = g / (1.0f + __expf(-1.702f * g));
          float a = (u + 1.0f) * glu;
          ActE[(size_t)(rowb + r) * (N / 2) + acol] = f2bf(a);
        }
      }
    }
  } else {
    float* OutE = Out + (size_t)e * M_ * N;
    const float* be = bias + (size_t)e * N;
    #pragma unroll
    for (int ni = 0; ni < 4; ++ni) {
      int col = n0 + wn * 64 + ni * 16 + c;
      float bb = be[col];
      #pragma unroll
      for (int mi = 0; mi < 4; ++mi) {
        int rowb = m0 + wm * 64 + mi * 16 + q * 4;
        #pragma unroll
        for (int r = 0; r < 4; ++r)
          OutE[(size_t)(rowb + r) * N + col] = acc[mi][ni][r] + bb;
      }
    }
  }
}

// ---------------- scratch-free fallback (correct but slow) ----------------
__global__ __launch_bounds__(256) void k_naive(const float* __restrict__ disp,
    const float* __restrict__ w1, const float* __restrict__ w1b,
    const float* __restrict__ w2, const float* __restrict__ w2b,
    float* __restrict__ out) {
  __shared__ float xrow[H_];
  __shared__ float act[INTER_];
  int b = blockIdx.x;
  int e = b / M_;
  int m = b % M_;
  const float* x = disp + (size_t)(e * M_ + m) * H_;
  int tid = threadIdx.x;
  for (int k = tid; k < H_; k += 256) xrow[k] = x[k];
  __syncthreads();
  const float* w1e = w1 + (size_t)e * H_ * I2_;
  const float* b1e = w1b + (size_t)e * I2_;
  for (int jj = 0; jj < INTER_ / 256; ++jj) {
    int i = tid + jj * 256;
    float g = b1e[2 * i], u = b1e[2 * i + 1];
    for (int k = 0; k < H_; ++k) {
      float xv = xrow[k];
      g += xv * w1e[(size_t)k * I2_ + 2 * i];
      u += xv * w1e[(size_t)k * I2_ + 2 * i + 1];
    }
    g = fminf(g, 7.0f);
    u = fminf(fmaxf(u, -7.0f), 7.0f);
    float glu = g / (1.0f + __expf(-1.702f * g));
    act[i] = (u + 1.0f) * glu;
  }
  __syncthreads();
  const float* w2e = w2 + (size_t)e * INTER_ * H_;
  const float* b2e = w2b + (size_t)e * H_;
  float* oute = out + (size_t)(e * M_ + m) * H_;
  for (int jj = 0; jj < H_ / 256; ++jj) {
    int h = tid + jj * 256;
    float o = b2e[h];
    for (int i = 0; i < INTER_; ++i) o += act[i] * w2e[(size_t)i * H_ + h];
    oute[h] = o;
  }
}

extern "C" void kernel_launch(void* const* d_in, const int* in_sizes, int n_in,
                              void* d_out, int out_size, void* d_ws, size_t ws_size,
                              hipStream_t stream) {
  const float* disp = (const float*)d_in[0];
  const float* w1   = (const float*)d_in[1];
  const float* w1b  = (const float*)d_in[2];
  const float* w2   = (const float*)d_in[3];
  const float* w2b  = (const float*)d_in[4];
  float* out = (float*)d_out;

  const size_t nA   = (size_t)E_ * M_ * H_;       // 16.7M
  const size_t nAct = (size_t)E_ * M_ * INTER_;   // 16.7M
  const size_t need = (nA + nAct) * 2;            // 67 MB

  if (ws_size >= need) {
    unsigned short* actb = (unsigned short*)d_ws;
    unsigned short* ab   = actb + nAct;

    k_cvt<<<4096, 256, 0, stream>>>(disp, ab, (int)(nA / 4));
    k_gemm<1, I2_, H_><<<dim3(I2_ / 128, M_ / 128, E_), 256, 0, stream>>>(ab, w1, w1b, actb, nullptr);
    k_gemm<0, H_, INTER_><<<dim3(H_ / 128, M_ / 128, E_), 256, 0, stream>>>(actb, w2, w2b, nullptr, out);
  } else {
    k_naive<<<E_ * M_, 256, 0, stream>>>(disp, w1, w1b, w2, w2b, out);
  }
}